// Round 11
// baseline (264.487 us; speedup 1.0000x reference)
//
#include <hip/hip_runtime.h>

#define NB 16
#define NA 32
#define NG 512
#define NS 1024
#define NM 8
#define NE 5
#define NOH 20
#define NFE 100
#define ND 512
#define NBINS 512
#define NTOK (NB * NS)

typedef unsigned short ushort_t;
typedef __attribute__((ext_vector_type(8))) short bf16x8;
typedef __attribute__((ext_vector_type(4))) float f32x4;

__device__ __forceinline__ ushort_t f2bf(float x) {
  union { float f; unsigned u; } v; v.f = x;
  unsigned r = v.u + 0x7FFF + ((v.u >> 16) & 1);   // RNE
  return (ushort_t)(r >> 16);
}
__device__ __forceinline__ float bf2f(ushort_t b) {
  union { unsigned u; float f; } v; v.u = ((unsigned)b) << 16;
  return v.f;
}

__device__ __forceinline__ void gload_lds16(const void* g, void* l) {
  __builtin_amdgcn_global_load_lds(
      (const __attribute__((address_space(1))) void*)g,
      (__attribute__((address_space(3))) void*)l, 16, 0, 0);
}

// wave-wide (64 lanes) butterfly sum; all lanes get result
__device__ __forceinline__ float wsum64(float v) {
#pragma unroll
  for (int off = 32; off > 0; off >>= 1) v += __shfl_xor(v, off);
  return v;
}

// fast native sigmoid/tanh (v_exp_f32 + v_rcp_f32; err ~1e-6 << bf16 rounding)
__device__ __forceinline__ float fsig(float x) {
  return __builtin_amdgcn_rcpf(1.f + __expf(-x));   // x<-88: exp->inf, rcp->0 (correct)
}
__device__ __forceinline__ float ftanh(float x) {
  float t = fminf(fmaxf(x, -15.f), 15.f);           // keep exp finite; tanh sat by |x|>9
  return 1.f - 2.f * __builtin_amdgcn_rcpf(__expf(2.f * t) + 1.f);
}

// ---------- fused setup: invcnt | PS prefix table | weight cvt | VmT | S_bf ----------
__global__ __launch_bounds__(256) void setup_kernel(
    const float* __restrict__ vert, const float* __restrict__ mask,
    const float* __restrict__ eloh, const int* __restrict__ subs,
    const float* __restrict__ Wih, const float* __restrict__ Whh,
    const float* __restrict__ W1, const float* __restrict__ W2a,
    const float* __restrict__ W2b,
    float* __restrict__ tcd, float* __restrict__ PS,
    ushort_t* __restrict__ o_hh, ushort_t* __restrict__ o1,
    ushort_t* __restrict__ o2a, ushort_t* __restrict__ o2b,
    ushort_t* __restrict__ VmT, ushort_t* __restrict__ S_bf) {
  int i = blockIdx.x * 256 + threadIdx.x;
  if (i < NTOK) {   // per-token subset-size inverse + element counts (fp32 exact)
    int b = i >> 10;
    const int* srow = subs + (size_t)i * NA;
    float cnt[NE] = {0.f, 0.f, 0.f, 0.f, 0.f};
    float z = 0.f;
    for (int a = 0; a < NA; a++) {
      float sb = (float)srow[a];
      z += sb * mask[b * NA + a];
      const float* eo = eloh + (size_t)(b * NA + a) * NE;
#pragma unroll
      for (int e = 0; e < NE; e++) cnt[e] += eo[e] * sb;
    }
    float* o = tcd + (size_t)i * 8;
#pragma unroll
    for (int e = 0; e < NE; e++) o[e] = cnt[e];
    o[5] = 1.0f / (z + 1e-4f);
    return;
  }
  i -= NTOK;
  if (i < NE * 1536) {   // PS[e][c][g] = sum_{o<c} W_ih[g][e*20+o], fp32 exact
    int e = i / 1536, g = i % 1536;
    float s = 0.f;
    float* base = PS + ((size_t)e * 21) * 1536 + g;
    base[0] = 0.f;
    for (int c = 1; c <= NOH; c++) {
      s += Wih[(size_t)g * NFE + e * NOH + (c - 1)];
      base[(size_t)c * 1536] = s;
    }
    return;
  }
  i -= NE * 1536;
  if (i < 1536 * NG) { o_hh[i] = f2bf(Whh[i]); return; }
  i -= 1536 * NG;
  if (i < ND * NG) { o1[i] = f2bf(W1[i]); return; }
  i -= ND * NG;
  if (i < ND * ND) { o2a[i] = f2bf(W2a[i]); return; }
  i -= ND * ND;
  if (i < ND * ND) { o2b[i] = f2bf(W2b[i]); return; }
  i -= ND * ND;
  const int nV = NB * NG * NA;
  if (i < nV) {   // VmT[b][f][a] = bf16(vert*mask^2)
    int b = i / (NG * NA); int rem = i % (NG * NA);
    int f = rem >> 5, a = rem & 31;
    float mk = mask[b * NA + a];
    VmT[i] = f2bf(vert[(size_t)b * NA * NG + a * NG + f] * mk * mk);
    return;
  }
  i -= nV;
  if (i < NTOK * NA) S_bf[i] = f2bf((float)subs[i]);   // 0/1 exact
}

// ---------- pool GEMM: SWV[ltok][f] = (subs @ VmT^T) * inv  (K=32, one MFMA step) ----------
__global__ __launch_bounds__(256) void pool_gemm(
    const ushort_t* __restrict__ S_bf, const ushort_t* __restrict__ VmT,
    const float* __restrict__ tcd, float* __restrict__ SWV, int tok0) {
  __shared__ ushort_t As[128 * 32];
  __shared__ ushort_t Bs[128 * 32];
  const int t = threadIdx.x;
  const int w = t >> 6, lane = t & 63;
  const int wr = w >> 1, wc = w & 1;
  const int bm = blockIdx.x * 128;   // chunk-local token base
  const int bn = blockIdx.y * 128;   // f base
  const int b = (tok0 + bm) >> 10;   // 128 | 1024 so tile is single-batch
  const int srow = lane >> 2;
  const int scol = (((lane & 3) ^ ((lane >> 3) & 3)) * 8);   // pre-swizzled source chunk
  const ushort_t* Bbase = VmT + (size_t)b * NG * NA;
  gload_lds16(S_bf + (size_t)(tok0 + bm + w * 16 + srow) * 32 + scol, &As[w * 512]);
  gload_lds16(S_bf + (size_t)(tok0 + bm + 64 + w * 16 + srow) * 32 + scol, &As[2048 + w * 512]);
  gload_lds16(Bbase + (size_t)(bn + w * 16 + srow) * 32 + scol, &Bs[w * 512]);
  gload_lds16(Bbase + (size_t)(bn + 64 + w * 16 + srow) * 32 + scol, &Bs[2048 + w * 512]);
  __syncthreads();

  const int lr = lane & 15, lq = lane >> 4;
  const int rchunk = (lq ^ ((lr >> 1) & 3)) * 8;   // swizzled read chunk
  f32x4 acc[4][4];
#pragma unroll
  for (int m = 0; m < 4; m++)
#pragma unroll
    for (int n = 0; n < 4; n++) acc[m][n] = (f32x4)0.f;
  bf16x8 a[4], bb[4];
#pragma unroll
  for (int m = 0; m < 4; m++)
    a[m] = *(const bf16x8*)&As[(wr * 64 + m * 16 + lr) * 32 + rchunk];
#pragma unroll
  for (int n = 0; n < 4; n++)
    bb[n] = *(const bf16x8*)&Bs[(wc * 64 + n * 16 + lr) * 32 + rchunk];
#pragma unroll
  for (int m = 0; m < 4; m++)
#pragma unroll
    for (int n = 0; n < 4; n++)
      acc[m][n] = __builtin_amdgcn_mfma_f32_16x16x32_bf16(a[m], bb[n], acc[m][n], 0, 0, 0);

#pragma unroll
  for (int n = 0; n < 4; n++) {
    const int col = bn + wc * 64 + n * 16 + lr;
#pragma unroll
    for (int m = 0; m < 4; m++) {
      f32x4 v = acc[m][n];
#pragma unroll
      for (int r = 0; r < 4; r++) {
        int row = bm + wr * 64 + m * 16 + lq * 4 + r;
        float inv = tcd[(size_t)(tok0 + row) * 8 + 5];
        SWV[(size_t)row * NG + col] = v[r] * inv;
      }
    }
  }
}

// ---------- finish: LN(swv_mean) -> Hb bf16 (wave per token, 4 tokens/block) ----------
__global__ __launch_bounds__(256) void finish_kernel(
    const float* __restrict__ SWV, const float* __restrict__ lng,
    const float* __restrict__ lnb, ushort_t* __restrict__ Hb) {
  const int t = threadIdx.x;
  const int lane = t & 63, wv = t >> 6;
  const int ltok = blockIdx.x * 4 + wv;
  const int f = lane * 8;
  const float* row = SWV + (size_t)ltok * NG + f;
  float4 v0 = *(const float4*)row;
  float4 v1 = *(const float4*)(row + 4);
  float x[8] = {v0.x, v0.y, v0.z, v0.w, v1.x, v1.y, v1.z, v1.w};
  float ps = 0.f;
#pragma unroll
  for (int j = 0; j < 8; j++) ps += x[j];
  float mean = wsum64(ps) * (1.0f / NG);
  float pq = 0.f;
#pragma unroll
  for (int j = 0; j < 8; j++) { float d = x[j] - mean; pq += d * d; }
  float rstd = rsqrtf(wsum64(pq) * (1.0f / NG) + 1e-5f);
  float4 g0 = *(const float4*)&lng[f], g1 = *(const float4*)&lng[f + 4];
  float4 b0 = *(const float4*)&lnb[f], b1 = *(const float4*)&lnb[f + 4];
  float gg[8] = {g0.x, g0.y, g0.z, g0.w, g1.x, g1.y, g1.z, g1.w};
  float bbv[8] = {b0.x, b0.y, b0.z, b0.w, b1.x, b1.y, b1.z, b1.w};
  bf16x8 ho;
#pragma unroll
  for (int j = 0; j < 8; j++) ho[j] = (short)f2bf((x[j] - mean) * rstd * gg[j] + bbv[j]);
  *(bf16x8*)&Hb[(size_t)ltok * NG + f] = ho;
}

// ---------- bf16 MFMA GEMM, 2-phase double-buffer (compiler-scheduled) ----------
// BM=BN=128, BK=32, 4 waves (2x2), 4x4 16x16x32 frags per wave.
// mode: 1 = bf16 out relu, 3 = bf16 out no act
__global__ __launch_bounds__(256) void gemm_bf16(
    const ushort_t* __restrict__ A, const ushort_t* __restrict__ W,
    const float* __restrict__ bias, ushort_t* __restrict__ C,
    int K, int Dout, int mode) {
  __shared__ ushort_t As[2][4096];
  __shared__ ushort_t Bs[2][4096];
  const int t = threadIdx.x;
  const int w = t >> 6;
  const int lane = t & 63;
  const int wr = w >> 1, wc = w & 1;
  const int bm = blockIdx.x * 128, bn = blockIdx.y * 128;

  const int srow = lane >> 2;
  const int scol = (((lane & 3) ^ ((lane >> 3) & 3)) * 8);   // pre-swizzled source chunk
  const ushort_t* Ag0 = A + (size_t)(bm + w * 16 + srow) * K + scol;
  const ushort_t* Ag1 = A + (size_t)(bm + 64 + w * 16 + srow) * K + scol;
  const ushort_t* Wg0 = W + (size_t)(bn + w * 16 + srow) * K + scol;
  const ushort_t* Wg1 = W + (size_t)(bn + 64 + w * 16 + srow) * K + scol;
  const int l0 = w * 512;          // ushort offset, issue 0 (rows w*16..+16)
  const int l1 = 2048 + w * 512;   // issue 1 (rows 64+w*16..+16)

  const int lr = lane & 15;
  const int lq = lane >> 4;
  const int rchunk = (lq ^ ((lr >> 1) & 3)) * 8;   // swizzled read chunk

  f32x4 acc[4][4];
#pragma unroll
  for (int m = 0; m < 4; m++)
#pragma unroll
    for (int n = 0; n < 4; n++) acc[m][n] = (f32x4)0.f;

  // prologue: stage tile 0 into buf 0
  gload_lds16(Ag0, &As[0][l0]);
  gload_lds16(Ag1, &As[0][l1]);
  gload_lds16(Wg0, &Bs[0][l0]);
  gload_lds16(Wg1, &Bs[0][l1]);
  __syncthreads();

  const int nk = K >> 5;
  int cur = 0;
  for (int kt = 0; kt < nk; kt++) {
    if (kt + 1 < nk) {            // prefetch next tile into other buffer
      const int k1 = (kt + 1) << 5;
      gload_lds16(Ag0 + k1, &As[cur ^ 1][l0]);
      gload_lds16(Ag1 + k1, &As[cur ^ 1][l1]);
      gload_lds16(Wg0 + k1, &Bs[cur ^ 1][l0]);
      gload_lds16(Wg1 + k1, &Bs[cur ^ 1][l1]);
    }
    bf16x8 a[4], b[4];
#pragma unroll
    for (int m = 0; m < 4; m++)
      a[m] = *(const bf16x8*)&As[cur][(wr * 64 + m * 16 + lr) * 32 + rchunk];
#pragma unroll
    for (int n = 0; n < 4; n++)
      b[n] = *(const bf16x8*)&Bs[cur][(wc * 64 + n * 16 + lr) * 32 + rchunk];
#pragma unroll
    for (int m = 0; m < 4; m++)
#pragma unroll
      for (int n = 0; n < 4; n++)
        acc[m][n] = __builtin_amdgcn_mfma_f32_16x16x32_bf16(a[m], b[n], acc[m][n], 0, 0, 0);
    __syncthreads();   // drains lgkm (buf reads) and vm (prefetch) before swap
    cur ^= 1;
  }

  // ---- epilogue: per-wave LDS re-stage -> coalesced stores ----
  ushort_t* sc = (w < 2) ? &As[w][0] : &Bs[w - 2][0];   // 4096 ushorts = 64x64 tile
#pragma unroll
  for (int n = 0; n < 4; n++) {
    const float bv = bias[bn + wc * 64 + n * 16 + lr];
#pragma unroll
    for (int m = 0; m < 4; m++) {
      f32x4 v = acc[m][n];
#pragma unroll
      for (int r = 0; r < 4; r++) {
        const int row = m * 16 + lq * 4 + r;
        float u = v[r] + bv;
        if (mode == 1) u = fmaxf(u, 0.f);
        sc[row * 64 + ((n * 16 + lr) ^ ((row & 7) << 3))] = f2bf(u);
      }
    }
  }
  __builtin_amdgcn_s_waitcnt(0);   // lgkmcnt(0): ds_writes visible to own-wave reads
#pragma unroll
  for (int p = 0; p < 8; p++) {
    const int row = p * 8 + (lane >> 3);
    bf16x8 pk = *(const bf16x8*)&sc[row * 64 + (((lane & 7) * 8) ^ ((row & 7) << 3))];
    *(bf16x8*)&C[(size_t)(bm + wr * 64 + row) * Dout + bn + wc * 64 + (lane & 7) * 8] = pk;
  }
}

// ---------- GRU gates + post-LN, gi via PS gather (wave per token) ----------
__global__ __launch_bounds__(256) void gate_ln_kernel(
    const ushort_t* __restrict__ Gh, const ushort_t* __restrict__ Hb,
    const float* __restrict__ tcd, const float* __restrict__ PS,
    const float* __restrict__ b_ih, const float* __restrict__ lng,
    const float* __restrict__ lnb, ushort_t* __restrict__ X0) {
  const int t = threadIdx.x;
  const int lane = t & 63, wv = t >> 6;
  const int ltok = blockIdx.x * 4 + wv;
  const int f = lane * 8;
  int c[NE];
#pragma unroll
  for (int e = 0; e < NE; e++) {
    int ci = (int)tcd[(size_t)ltok * 8 + e];   // exact integer-valued fp32
    c[e] = ci > NOH ? NOH : ci;
  }
  float4 r0 = *(const float4*)&b_ih[f],          r1 = *(const float4*)&b_ih[f + 4];
  float4 z0 = *(const float4*)&b_ih[NG + f],     z1 = *(const float4*)&b_ih[NG + f + 4];
  float4 n0 = *(const float4*)&b_ih[2 * NG + f], n1 = *(const float4*)&b_ih[2 * NG + f + 4];
#pragma unroll
  for (int e = 0; e < NE; e++) {
    const float* pe = PS + ((size_t)(e * 21 + c[e])) * 1536;
    r0 += *(const float4*)&pe[f];          r1 += *(const float4*)&pe[f + 4];
    z0 += *(const float4*)&pe[NG + f];     z1 += *(const float4*)&pe[NG + f + 4];
    n0 += *(const float4*)&pe[2 * NG + f]; n1 += *(const float4*)&pe[2 * NG + f + 4];
  }
  float gir[8] = {r0.x, r0.y, r0.z, r0.w, r1.x, r1.y, r1.z, r1.w};
  float giz[8] = {z0.x, z0.y, z0.z, z0.w, z1.x, z1.y, z1.z, z1.w};
  float gin[8] = {n0.x, n0.y, n0.z, n0.w, n1.x, n1.y, n1.z, n1.w};

  const ushort_t* gh = Gh + (size_t)ltok * 1536;
  bf16x8 vr = *(const bf16x8*)&gh[f];
  bf16x8 vz = *(const bf16x8*)&gh[NG + f];
  bf16x8 vn = *(const bf16x8*)&gh[2 * NG + f];
  bf16x8 vh = *(const bf16x8*)&Hb[(size_t)ltok * NG + f];
  float cv[8];
  float ps = 0.f;
#pragma unroll
  for (int j = 0; j < 8; j++) {
    float rg = fsig(gir[j] + bf2f((ushort_t)vr[j]));
    float zg = fsig(giz[j] + bf2f((ushort_t)vz[j]));
    float ng = ftanh(gin[j] + rg * bf2f((ushort_t)vn[j]));
    cv[j] = (1.f - zg) * ng + zg * bf2f((ushort_t)vh[j]);
    ps += cv[j];
  }
  float mean = wsum64(ps) * (1.0f / NG);
  float pq = 0.f;
#pragma unroll
  for (int j = 0; j < 8; j++) { float d = cv[j] - mean; pq += d * d; }
  float rstd = rsqrtf(wsum64(pq) * (1.0f / NG) + 1e-5f);
  float4 g0 = *(const float4*)&lng[f], g1 = *(const float4*)&lng[f + 4];
  float4 b0 = *(const float4*)&lnb[f], b1 = *(const float4*)&lnb[f + 4];
  float gg[8] = {g0.x, g0.y, g0.z, g0.w, g1.x, g1.y, g1.z, g1.w};
  float bbv[8] = {b0.x, b0.y, b0.z, b0.w, b1.x, b1.y, b1.z, b1.w};
  bf16x8 xo;
#pragma unroll
  for (int j = 0; j < 8; j++) xo[j] = (short)f2bf((cv[j] - mean) * rstd * gg[j] + bbv[j]);
  *(bf16x8*)&X0[(size_t)ltok * NG + f] = xo;
}

// ---------- fused FFN (W1+W2a+W2b) + final LN + score, barrier-free reg-B GEMM ----------
// 64 tokens/block, 512 threads (8 waves). Activations ping-pong in LDS (XOR-swizzled
// chunk^(row&7)); B-fragments load directly global->VGPR (wave covers 16 full 64B lines
// of L2-resident weights). K-loop has no barriers -> compiler pipelines loads under MFMA.
__device__ __forceinline__ void ffn_layer(
    const ushort_t* src, ushort_t* dst, const ushort_t* __restrict__ Wl,
    const float* __restrict__ bl, const int w, const int lane) {
  const int lr = lane & 15, lq = lane >> 4;
  const int cw = w * 64;
  const int sw = lr & 7;                  // row&7 for A-frag rows (m*16+lr)
  f32x4 acc[4][4];
#pragma unroll
  for (int m = 0; m < 4; m++)
#pragma unroll
    for (int n = 0; n < 4; n++) acc[m][n] = (f32x4)0.f;
  const ushort_t* wp0 = Wl + (size_t)(cw + 0 + lr) * 512 + lq * 8;
  const ushort_t* wp1 = Wl + (size_t)(cw + 16 + lr) * 512 + lq * 8;
  const ushort_t* wp2 = Wl + (size_t)(cw + 32 + lr) * 512 + lq * 8;
  const ushort_t* wp3 = Wl + (size_t)(cw + 48 + lr) * 512 + lq * 8;
#pragma unroll
  for (int kt = 0; kt < 16; kt++) {
    bf16x8 a[4], b[4];
    const int ch = (kt * 4 + lq) ^ sw;
#pragma unroll
    for (int m = 0; m < 4; m++)
      a[m] = *(const bf16x8*)&src[(m * 16 + lr) * 512 + ch * 8];
    b[0] = *(const bf16x8*)(wp0 + kt * 32);
    b[1] = *(const bf16x8*)(wp1 + kt * 32);
    b[2] = *(const bf16x8*)(wp2 + kt * 32);
    b[3] = *(const bf16x8*)(wp3 + kt * 32);
#pragma unroll
    for (int m = 0; m < 4; m++)
#pragma unroll
      for (int n = 0; n < 4; n++)
        acc[m][n] = __builtin_amdgcn_mfma_f32_16x16x32_bf16(a[m], b[n], acc[m][n], 0, 0, 0);
  }
  // epilogue: bias + relu + bf16 -> swizzled LDS write (C layout: col=lane&15 group)
#pragma unroll
  for (int n = 0; n < 4; n++) {
    const int c = cw + n * 16 + lr;
    const float bv = bl[c];
#pragma unroll
    for (int m = 0; m < 4; m++) {
      f32x4 v = acc[m][n];
#pragma unroll
      for (int r = 0; r < 4; r++) {
        const int row = m * 16 + lq * 4 + r;
        float u = fmaxf(v[r] + bv, 0.f);
        dst[row * 512 + (((c >> 3) ^ (row & 7)) << 3) + (c & 7)] = f2bf(u);
      }
    }
  }
}

__global__ __launch_bounds__(512) void ffn_kernel(
    const ushort_t* __restrict__ X0g, const ushort_t* __restrict__ W1l,
    const float* __restrict__ b1l, const ushort_t* __restrict__ W2al,
    const float* __restrict__ b2al, const ushort_t* __restrict__ W2bl,
    const float* __restrict__ b2bl, const float* __restrict__ lng,
    const float* __restrict__ lnb, const float* __restrict__ Wsc,
    const float* __restrict__ bsc, float* __restrict__ scores, int tok0) {
  __shared__ ushort_t Xa[64 * 512];
  __shared__ ushort_t Xb[64 * 512];
  const int t = threadIdx.x;
  const int w = t >> 6, lane = t & 63;
  const int tb = blockIdx.x * 64;   // chunk-local token base
  // stage X0 tile: linear LDS dest (rule 21), pre-swizzled global source.
  // issue i: rows i*8+w (one row per wave); lds chunk=lane holds logical chunk lane^w.
#pragma unroll
  for (int i = 0; i < 8; i++) {
    const int row = i * 8 + w;
    gload_lds16(X0g + (size_t)(tok0 + tb + row) * 512 + ((lane ^ w) << 3),
                &Xa[i * 4096 + w * 512]);
  }
  __syncthreads();
  ffn_layer(Xa, Xb, W1l, b1l, w, lane);
  __syncthreads();
  ffn_layer(Xb, Xa, W2al, b2al, w, lane);
  __syncthreads();
  ffn_layer(Xa, Xb, W2bl, b2bl, w, lane);
  __syncthreads();
  // final LN + score on X3 (in Xb); 8 rows per wave
#pragma unroll
  for (int j = 0; j < 8; j++) {
    const int row = w * 8 + j;
    bf16x8 xx = *(const bf16x8*)&Xb[row * 512 + ((lane ^ (row & 7)) << 3)];
    float x[8];
    float ps = 0.f;
#pragma unroll
    for (int q = 0; q < 8; q++) { x[q] = bf2f((ushort_t)xx[q]); ps += x[q]; }
    float mean = wsum64(ps) * (1.0f / ND);
    float pq = 0.f;
#pragma unroll
    for (int q = 0; q < 8; q++) { float d = x[q] - mean; pq += d * d; }
    float rstd = rsqrtf(wsum64(pq) * (1.0f / ND) + 1e-5f);
    const int f = lane * 8;
    float4 g0 = *(const float4*)&lng[f], g1 = *(const float4*)&lng[f + 4];
    float4 e0 = *(const float4*)&lnb[f], e1 = *(const float4*)&lnb[f + 4];
    float4 s0 = *(const float4*)&Wsc[f], s1 = *(const float4*)&Wsc[f + 4];
    float gg[8] = {g0.x, g0.y, g0.z, g0.w, g1.x, g1.y, g1.z, g1.w};
    float bv[8] = {e0.x, e0.y, e0.z, e0.w, e1.x, e1.y, e1.z, e1.w};
    float ww[8] = {s0.x, s0.y, s0.z, s0.w, s1.x, s1.y, s1.z, s1.w};
    float d = 0.f;
#pragma unroll
    for (int q = 0; q < 8; q++) d += ((x[q] - mean) * rstd * gg[q] + bv[q]) * ww[q];
    float dot = wsum64(d);
    if (lane == 0) scores[tok0 + tb + row] = dot + bsc[0];
  }
}

// ---------- fused softmax + LDS-spectrum scatter (one block per batch) ----------
__global__ __launch_bounds__(256) void softmax_scatter_kernel(
    const float* __restrict__ scores, const int* __restrict__ pidx,
    const float* __restrict__ pint, float* __restrict__ spect,
    float* __restrict__ probs) {
  const int b = blockIdx.x;
  const int t = threadIdx.x;
  __shared__ float s_red[4];
  __shared__ float s_spec[NBINS];
  const float* sc = scores + (size_t)b * NS;
  float v[4];
  float mx = -1e30f;
#pragma unroll
  for (int i = 0; i < 4; i++) { v[i] = sc[t + i * 256]; mx = fmaxf(mx, v[i]); }
#pragma unroll
  for (int off = 32; off > 0; off >>= 1) mx = fmaxf(mx, __shfl_down(mx, off));
  if ((t & 63) == 0) s_red[t >> 6] = mx;
  __syncthreads();
  mx = fmaxf(fmaxf(s_red[0], s_red[1]), fmaxf(s_red[2], s_red[3]));
  float e[4], sum = 0.f;
#pragma unroll
  for (int i = 0; i < 4; i++) { e[i] = expf(v[i] - mx); sum += e[i]; }
#pragma unroll
  for (int off = 32; off > 0; off >>= 1) sum += __shfl_down(sum, off);
  __syncthreads();
  if ((t & 63) == 0) s_red[t >> 6] = sum;
  __syncthreads();
  sum = s_red[0] + s_red[1] + s_red[2] + s_red[3];
  float inv = 1.f / sum;
  s_spec[t] = 0.f; s_spec[t + 256] = 0.f;
  float p[4];
#pragma unroll
  for (int i = 0; i < 4; i++) {
    p[i] = e[i] * inv;
    probs[(size_t)b * NS + t + i * 256] = p[i];
  }
  __syncthreads();
#pragma unroll
  for (int i = 0; i < 4; i++) {
    const int s = t + i * 256;
    const int* idx = pidx + ((size_t)b * NS + s) * NM;
    const float* wt = pint + ((size_t)b * NS + s) * NM;
#pragma unroll
    for (int m = 0; m < NM; m++)
      atomicAdd(&s_spec[idx[m]], wt[m] * p[i]);
  }
  __syncthreads();
  spect[(size_t)b * NBINS + t] = s_spec[t];
  spect[(size_t)b * NBINS + t + 256] = s_spec[t + 256];
}

extern "C" void kernel_launch(void* const* d_in, const int* in_sizes, int n_in,
                              void* d_out, int out_size, void* d_ws, size_t ws_size,
                              hipStream_t stream) {
  const float* vert = (const float*)d_in[0];
  const float* mask = (const float*)d_in[1];
  const float* eloh = (const float*)d_in[2];
  const int* subs = (const int*)d_in[3];
  const int* pidx = (const int*)d_in[4];
  const float* pint = (const float*)d_in[5];
  const float* ln_sub_g = (const float*)d_in[6];
  const float* ln_sub_b = (const float*)d_in[7];
  const float* W_ih = (const float*)d_in[8];
  const float* W_hh = (const float*)d_in[9];
  const float* b_ih = (const float*)d_in[10];
  const float* b_hh = (const float*)d_in[11];
  const float* ln_post_g = (const float*)d_in[12];
  const float* ln_post_b = (const float*)d_in[13];
  const float* W1 = (const float*)d_in[14];
  const float* b1 = (const float*)d_in[15];
  const float* W2a = (const float*)d_in[16];
  const float* b2a = (const float*)d_in[17];
  const float* W2b = (const float*)d_in[18];
  const float* b2b = (const float*)d_in[19];
  const float* ln_pre_g = (const float*)d_in[20];
  const float* ln_pre_b = (const float*)d_in[21];
  const float* W_s = (const float*)d_in[22];
  const float* b_s = (const float*)d_in[23];

  float* out = (float*)d_out;            // [0,8192) spect, [8192,24576) probs
  float* probs = out + NB * NBINS;

  // ---- fixed region ----
  char* ws = (char*)d_ws;
  float* scores = (float*)ws;                       // 64 KB
  ushort_t* Whh_bf = (ushort_t*)(ws + 65536);       // 1536*512*2 = 1572864
  ushort_t* W1_bf  = (ushort_t*)(ws + 1638400);     // 512*512*2 = 524288
  ushort_t* W2a_bf = (ushort_t*)(ws + 2162688);
  ushort_t* W2b_bf = (ushort_t*)(ws + 2686976);
  ushort_t* VmT    = (ushort_t*)(ws + 3211264);     // 16*512*32*2 = 524288
  ushort_t* S_bf   = (ushort_t*)(ws + 3735552);     // 16384*32*2 = 1048576
  float*    tcd    = (float*)(ws + 4784128);        // 16384*8*4 = 524288
  float*    PS     = (float*)(ws + 5308416);        // 5*21*1536*4 = 645120
  const size_t fixed = 5953536;

  // ---- chunked region; per-token bytes: SWV 2048 | Hb 1024 | Gh 3072 | X0 1024 = 7168
  const size_t per_tok = 7168;
  int T = NTOK;
  while (T > 1024 && fixed + (size_t)T * per_tok > ws_size) T >>= 1;
  const int nchunks = NTOK / T;

  char* cb = ws + fixed;
  float*    SWV = (float*)cb;                             cb += (size_t)T * 2048;
  ushort_t* Hb  = (ushort_t*)cb;                          cb += (size_t)T * 1024;
  ushort_t* Gh  = (ushort_t*)cb;                          cb += (size_t)T * 3072;
  ushort_t* X0  = (ushort_t*)cb;

  // fused setup: invcnt + PS prefix table + 4 weight cvts + VmT prep + S_bf cvt
  const int setup_items = NTOK + NE * 1536 + 1536 * NG + ND * NG + 2 * ND * ND
                        + NB * NG * NA + NTOK * NA;
  setup_kernel<<<(setup_items + 255) / 256, 256, 0, stream>>>(
      vert, mask, eloh, subs, W_ih, W_hh, W1, W2a, W2b,
      tcd, PS, Whh_bf, W1_bf, W2a_bf, W2b_bf, VmT, S_bf);

  for (int c = 0; c < nchunks; c++) {
    const int tok0 = c * T;

    dim3 gp(T / 128, NG / 128);
    pool_gemm<<<gp, 256, 0, stream>>>(S_bf, VmT, tcd, SWV, tok0);
    finish_kernel<<<T / 4, 256, 0, stream>>>(SWV, ln_sub_g, ln_sub_b, Hb);

    dim3 g1(T / 128, 1536 / 128);
    gemm_bf16<<<g1, 256, 0, stream>>>(Hb, Whh_bf, b_hh, Gh, NG, 1536, 3);

    gate_ln_kernel<<<T / 4, 256, 0, stream>>>(Gh, Hb, tcd + (size_t)tok0 * 8, PS,
                                              b_ih, ln_post_g, ln_post_b, X0);

    ffn_kernel<<<T / 64, 512, 0, stream>>>(X0, W1_bf, b1, W2a_bf, b2a, W2b_bf, b2b,
                                           ln_pre_g, ln_pre_b, W_s, b_s, scores, tok0);
  }

  softmax_scatter_kernel<<<NB, 256, 0, stream>>>(scores, pidx, pint, out, probs);
}

// Round 12
// 250.960 us; speedup vs baseline: 1.0539x; 1.0539x over previous
//
#include <hip/hip_runtime.h>

#define NB 16
#define NA 32
#define NG 512
#define NS 1024
#define NM 8
#define NE 5
#define NOH 20
#define NFE 100
#define ND 512
#define NBINS 512
#define NTOK (NB * NS)

typedef unsigned short ushort_t;
typedef __attribute__((ext_vector_type(8))) short bf16x8;
typedef __attribute__((ext_vector_type(4))) float f32x4;

__device__ __forceinline__ ushort_t f2bf(float x) {
  union { float f; unsigned u; } v; v.f = x;
  unsigned r = v.u + 0x7FFF + ((v.u >> 16) & 1);   // RNE
  return (ushort_t)(r >> 16);
}
__device__ __forceinline__ float bf2f(ushort_t b) {
  union { unsigned u; float f; } v; v.u = ((unsigned)b) << 16;
  return v.f;
}

__device__ __forceinline__ void gload_lds16(const void* g, void* l) {
  __builtin_amdgcn_global_load_lds(
      (const __attribute__((address_space(1))) void*)g,
      (__attribute__((address_space(3))) void*)l, 16, 0, 0);
}

// wave-wide (64 lanes) butterfly sum; all lanes get result
__device__ __forceinline__ float wsum64(float v) {
#pragma unroll
  for (int off = 32; off > 0; off >>= 1) v += __shfl_xor(v, off);
  return v;
}

// fast native sigmoid/tanh (v_exp_f32 + v_rcp_f32; err ~1e-6 << bf16 rounding)
__device__ __forceinline__ float fsig(float x) {
  return __builtin_amdgcn_rcpf(1.f + __expf(-x));   // x<-88: exp->inf, rcp->0 (correct)
}
__device__ __forceinline__ float ftanh(float x) {
  float t = fminf(fmaxf(x, -15.f), 15.f);           // keep exp finite; tanh sat by |x|>9
  return 1.f - 2.f * __builtin_amdgcn_rcpf(__expf(2.f * t) + 1.f);
}

// ---------- fused setup: invcnt | PS prefix table (bf16, b_ih folded) | weight cvt | VmT | S_bf ----------
__global__ __launch_bounds__(256) void setup_kernel(
    const float* __restrict__ vert, const float* __restrict__ mask,
    const float* __restrict__ eloh, const int* __restrict__ subs,
    const float* __restrict__ Wih, const float* __restrict__ bih,
    const float* __restrict__ Whh,
    const float* __restrict__ W1, const float* __restrict__ W2a,
    const float* __restrict__ W2b,
    float* __restrict__ tcd, ushort_t* __restrict__ PSb,
    ushort_t* __restrict__ o_hh, ushort_t* __restrict__ o1,
    ushort_t* __restrict__ o2a, ushort_t* __restrict__ o2b,
    ushort_t* __restrict__ VmT, ushort_t* __restrict__ S_bf) {
  int i = blockIdx.x * 256 + threadIdx.x;
  if (i < NTOK) {   // per-token subset-size inverse + element counts (fp32 exact)
    int b = i >> 10;
    const int* srow = subs + (size_t)i * NA;
    float cnt[NE] = {0.f, 0.f, 0.f, 0.f, 0.f};
    float z = 0.f;
    for (int a = 0; a < NA; a++) {
      float sb = (float)srow[a];
      z += sb * mask[b * NA + a];
      const float* eo = eloh + (size_t)(b * NA + a) * NE;
#pragma unroll
      for (int e = 0; e < NE; e++) cnt[e] += eo[e] * sb;
    }
    float* o = tcd + (size_t)i * 8;
#pragma unroll
    for (int e = 0; e < NE; e++) o[e] = cnt[e];
    o[5] = 1.0f / (z + 1e-4f);
    return;
  }
  i -= NTOK;
  if (i < NE * 1536) {   // PSb[e][c][g] = bf16( (e==0?b_ih[g]:0) + sum_{o<c} W_ih[g][e*20+o] )
    int e = i / 1536, g = i % 1536;
    float s = (e == 0) ? bih[g] : 0.f;    // fold bias into element-0 row (all c)
    ushort_t* base = PSb + ((size_t)e * 21) * 1536 + g;
    base[0] = f2bf(s);
    for (int c = 1; c <= NOH; c++) {
      s += Wih[(size_t)g * NFE + e * NOH + (c - 1)];
      base[(size_t)c * 1536] = f2bf(s);
    }
    return;
  }
  i -= NE * 1536;
  if (i < 1536 * NG) { o_hh[i] = f2bf(Whh[i]); return; }
  i -= 1536 * NG;
  if (i < ND * NG) { o1[i] = f2bf(W1[i]); return; }
  i -= ND * NG;
  if (i < ND * ND) { o2a[i] = f2bf(W2a[i]); return; }
  i -= ND * ND;
  if (i < ND * ND) { o2b[i] = f2bf(W2b[i]); return; }
  i -= ND * ND;
  const int nV = NB * NG * NA;
  if (i < nV) {   // VmT[b][f][a] = bf16(vert*mask^2)
    int b = i / (NG * NA); int rem = i % (NG * NA);
    int f = rem >> 5, a = rem & 31;
    float mk = mask[b * NA + a];
    VmT[i] = f2bf(vert[(size_t)b * NA * NG + a * NG + f] * mk * mk);
    return;
  }
  i -= nV;
  if (i < NTOK * NA) S_bf[i] = f2bf((float)subs[i]);   // 0/1 exact
}

// ---------- pool GEMM: SWV[ltok][f] = (subs @ VmT^T) * inv  (K=32, one MFMA step) ----------
__global__ __launch_bounds__(256) void pool_gemm(
    const ushort_t* __restrict__ S_bf, const ushort_t* __restrict__ VmT,
    const float* __restrict__ tcd, float* __restrict__ SWV, int tok0) {
  __shared__ ushort_t As[128 * 32];
  __shared__ ushort_t Bs[128 * 32];
  const int t = threadIdx.x;
  const int w = t >> 6, lane = t & 63;
  const int wr = w >> 1, wc = w & 1;
  const int bm = blockIdx.x * 128;   // chunk-local token base
  const int bn = blockIdx.y * 128;   // f base
  const int b = (tok0 + bm) >> 10;   // 128 | 1024 so tile is single-batch
  const int srow = lane >> 2;
  const int scol = (((lane & 3) ^ ((lane >> 3) & 3)) * 8);   // pre-swizzled source chunk
  const ushort_t* Bbase = VmT + (size_t)b * NG * NA;
  gload_lds16(S_bf + (size_t)(tok0 + bm + w * 16 + srow) * 32 + scol, &As[w * 512]);
  gload_lds16(S_bf + (size_t)(tok0 + bm + 64 + w * 16 + srow) * 32 + scol, &As[2048 + w * 512]);
  gload_lds16(Bbase + (size_t)(bn + w * 16 + srow) * 32 + scol, &Bs[w * 512]);
  gload_lds16(Bbase + (size_t)(bn + 64 + w * 16 + srow) * 32 + scol, &Bs[2048 + w * 512]);
  __syncthreads();

  const int lr = lane & 15, lq = lane >> 4;
  const int rchunk = (lq ^ ((lr >> 1) & 3)) * 8;   // swizzled read chunk
  f32x4 acc[4][4];
#pragma unroll
  for (int m = 0; m < 4; m++)
#pragma unroll
    for (int n = 0; n < 4; n++) acc[m][n] = (f32x4)0.f;
  bf16x8 a[4], bb[4];
#pragma unroll
  for (int m = 0; m < 4; m++)
    a[m] = *(const bf16x8*)&As[(wr * 64 + m * 16 + lr) * 32 + rchunk];
#pragma unroll
  for (int n = 0; n < 4; n++)
    bb[n] = *(const bf16x8*)&Bs[(wc * 64 + n * 16 + lr) * 32 + rchunk];
#pragma unroll
  for (int m = 0; m < 4; m++)
#pragma unroll
    for (int n = 0; n < 4; n++)
      acc[m][n] = __builtin_amdgcn_mfma_f32_16x16x32_bf16(a[m], bb[n], acc[m][n], 0, 0, 0);

#pragma unroll
  for (int n = 0; n < 4; n++) {
    const int col = bn + wc * 64 + n * 16 + lr;
#pragma unroll
    for (int m = 0; m < 4; m++) {
      f32x4 v = acc[m][n];
#pragma unroll
      for (int r = 0; r < 4; r++) {
        int row = bm + wr * 64 + m * 16 + lq * 4 + r;
        float inv = tcd[(size_t)(tok0 + row) * 8 + 5];
        SWV[(size_t)row * NG + col] = v[r] * inv;
      }
    }
  }
}

// ---------- finish: LN(swv_mean) -> Hb bf16 (wave per token, 4 tokens/block) ----------
__global__ __launch_bounds__(256) void finish_kernel(
    const float* __restrict__ SWV, const float* __restrict__ lng,
    const float* __restrict__ lnb, ushort_t* __restrict__ Hb) {
  const int t = threadIdx.x;
  const int lane = t & 63, wv = t >> 6;
  const int ltok = blockIdx.x * 4 + wv;
  const int f = lane * 8;
  const float* row = SWV + (size_t)ltok * NG + f;
  float4 v0 = *(const float4*)row;
  float4 v1 = *(const float4*)(row + 4);
  float x[8] = {v0.x, v0.y, v0.z, v0.w, v1.x, v1.y, v1.z, v1.w};
  float ps = 0.f;
#pragma unroll
  for (int j = 0; j < 8; j++) ps += x[j];
  float mean = wsum64(ps) * (1.0f / NG);
  float pq = 0.f;
#pragma unroll
  for (int j = 0; j < 8; j++) { float d = x[j] - mean; pq += d * d; }
  float rstd = rsqrtf(wsum64(pq) * (1.0f / NG) + 1e-5f);
  float4 g0 = *(const float4*)&lng[f], g1 = *(const float4*)&lng[f + 4];
  float4 b0 = *(const float4*)&lnb[f], b1 = *(const float4*)&lnb[f + 4];
  float gg[8] = {g0.x, g0.y, g0.z, g0.w, g1.x, g1.y, g1.z, g1.w};
  float bbv[8] = {b0.x, b0.y, b0.z, b0.w, b1.x, b1.y, b1.z, b1.w};
  bf16x8 ho;
#pragma unroll
  for (int j = 0; j < 8; j++) ho[j] = (short)f2bf((x[j] - mean) * rstd * gg[j] + bbv[j]);
  *(bf16x8*)&Hb[(size_t)ltok * NG + f] = ho;
}

// ---------- bf16 MFMA GEMM, 2-phase double-buffer (compiler-scheduled) ----------
// BM=BN=128, BK=32, 4 waves (2x2), 4x4 16x16x32 frags per wave.
// mode: 1 = bf16 out relu, 3 = bf16 out no act
__global__ __launch_bounds__(256) void gemm_bf16(
    const ushort_t* __restrict__ A, const ushort_t* __restrict__ W,
    const float* __restrict__ bias, ushort_t* __restrict__ C,
    int K, int Dout, int mode) {
  __shared__ ushort_t As[2][4096];
  __shared__ ushort_t Bs[2][4096];
  const int t = threadIdx.x;
  const int w = t >> 6;
  const int lane = t & 63;
  const int wr = w >> 1, wc = w & 1;
  const int bm = blockIdx.x * 128, bn = blockIdx.y * 128;

  const int srow = lane >> 2;
  const int scol = (((lane & 3) ^ ((lane >> 3) & 3)) * 8);   // pre-swizzled source chunk
  const ushort_t* Ag0 = A + (size_t)(bm + w * 16 + srow) * K + scol;
  const ushort_t* Ag1 = A + (size_t)(bm + 64 + w * 16 + srow) * K + scol;
  const ushort_t* Wg0 = W + (size_t)(bn + w * 16 + srow) * K + scol;
  const ushort_t* Wg1 = W + (size_t)(bn + 64 + w * 16 + srow) * K + scol;
  const int l0 = w * 512;          // ushort offset, issue 0 (rows w*16..+16)
  const int l1 = 2048 + w * 512;   // issue 1 (rows 64+w*16..+16)

  const int lr = lane & 15;
  const int lq = lane >> 4;
  const int rchunk = (lq ^ ((lr >> 1) & 3)) * 8;   // swizzled read chunk

  f32x4 acc[4][4];
#pragma unroll
  for (int m = 0; m < 4; m++)
#pragma unroll
    for (int n = 0; n < 4; n++) acc[m][n] = (f32x4)0.f;

  // prologue: stage tile 0 into buf 0
  gload_lds16(Ag0, &As[0][l0]);
  gload_lds16(Ag1, &As[0][l1]);
  gload_lds16(Wg0, &Bs[0][l0]);
  gload_lds16(Wg1, &Bs[0][l1]);
  __syncthreads();

  const int nk = K >> 5;
  int cur = 0;
  for (int kt = 0; kt < nk; kt++) {
    if (kt + 1 < nk) {            // prefetch next tile into other buffer
      const int k1 = (kt + 1) << 5;
      gload_lds16(Ag0 + k1, &As[cur ^ 1][l0]);
      gload_lds16(Ag1 + k1, &As[cur ^ 1][l1]);
      gload_lds16(Wg0 + k1, &Bs[cur ^ 1][l0]);
      gload_lds16(Wg1 + k1, &Bs[cur ^ 1][l1]);
    }
    bf16x8 a[4], b[4];
#pragma unroll
    for (int m = 0; m < 4; m++)
      a[m] = *(const bf16x8*)&As[cur][(wr * 64 + m * 16 + lr) * 32 + rchunk];
#pragma unroll
    for (int n = 0; n < 4; n++)
      b[n] = *(const bf16x8*)&Bs[cur][(wc * 64 + n * 16 + lr) * 32 + rchunk];
#pragma unroll
    for (int m = 0; m < 4; m++)
#pragma unroll
      for (int n = 0; n < 4; n++)
        acc[m][n] = __builtin_amdgcn_mfma_f32_16x16x32_bf16(a[m], b[n], acc[m][n], 0, 0, 0);
    __syncthreads();   // drains lgkm (buf reads) and vm (prefetch) before swap
    cur ^= 1;
  }

  // ---- epilogue: per-wave LDS re-stage -> coalesced stores ----
  ushort_t* sc = (w < 2) ? &As[w][0] : &Bs[w - 2][0];   // 4096 ushorts = 64x64 tile
#pragma unroll
  for (int n = 0; n < 4; n++) {
    const float bv = bias[bn + wc * 64 + n * 16 + lr];
#pragma unroll
    for (int m = 0; m < 4; m++) {
      f32x4 v = acc[m][n];
#pragma unroll
      for (int r = 0; r < 4; r++) {
        const int row = m * 16 + lq * 4 + r;
        float u = v[r] + bv;
        if (mode == 1) u = fmaxf(u, 0.f);
        sc[row * 64 + ((n * 16 + lr) ^ ((row & 7) << 3))] = f2bf(u);
      }
    }
  }
  __builtin_amdgcn_s_waitcnt(0);   // lgkmcnt(0): ds_writes visible to own-wave reads
#pragma unroll
  for (int p = 0; p < 8; p++) {
    const int row = p * 8 + (lane >> 3);
    bf16x8 pk = *(const bf16x8*)&sc[row * 64 + (((lane & 7) * 8) ^ ((row & 7) << 3))];
    *(bf16x8*)&C[(size_t)(bm + wr * 64 + row) * Dout + bn + wc * 64 + (lane & 7) * 8] = pk;
  }
}

// ---------- GRU gates + post-LN, gi via bf16 PS gather (bias folded) ----------
__global__ __launch_bounds__(256) void gate_ln_kernel(
    const ushort_t* __restrict__ Gh, const ushort_t* __restrict__ Hb,
    const float* __restrict__ tcd, const ushort_t* __restrict__ PSb,
    const float* __restrict__ lng, const float* __restrict__ lnb,
    ushort_t* __restrict__ X0) {
  const int t = threadIdx.x;
  const int lane = t & 63, wv = t >> 6;
  const int ltok = blockIdx.x * 4 + wv;
  const int f = lane * 8;
  int c[NE];
#pragma unroll
  for (int e = 0; e < NE; e++) {
    int ci = (int)tcd[(size_t)ltok * 8 + e];   // exact integer-valued fp32
    c[e] = ci > NOH ? NOH : ci;
  }
  float gir[8] = {0.f, 0.f, 0.f, 0.f, 0.f, 0.f, 0.f, 0.f};
  float giz[8] = {0.f, 0.f, 0.f, 0.f, 0.f, 0.f, 0.f, 0.f};
  float gin[8] = {0.f, 0.f, 0.f, 0.f, 0.f, 0.f, 0.f, 0.f};
#pragma unroll
  for (int e = 0; e < NE; e++) {
    const ushort_t* pe = PSb + ((size_t)(e * 21 + c[e])) * 1536;
    bf16x8 pr = *(const bf16x8*)&pe[f];
    bf16x8 pz = *(const bf16x8*)&pe[NG + f];
    bf16x8 pn = *(const bf16x8*)&pe[2 * NG + f];
#pragma unroll
    for (int j = 0; j < 8; j++) {
      gir[j] += bf2f((ushort_t)pr[j]);
      giz[j] += bf2f((ushort_t)pz[j]);
      gin[j] += bf2f((ushort_t)pn[j]);
    }
  }

  const ushort_t* gh = Gh + (size_t)ltok * 1536;
  bf16x8 vr = *(const bf16x8*)&gh[f];
  bf16x8 vz = *(const bf16x8*)&gh[NG + f];
  bf16x8 vn = *(const bf16x8*)&gh[2 * NG + f];
  bf16x8 vh = *(const bf16x8*)&Hb[(size_t)ltok * NG + f];
  float cv[8];
  float ps = 0.f;
#pragma unroll
  for (int j = 0; j < 8; j++) {
    float rg = fsig(gir[j] + bf2f((ushort_t)vr[j]));
    float zg = fsig(giz[j] + bf2f((ushort_t)vz[j]));
    float ng = ftanh(gin[j] + rg * bf2f((ushort_t)vn[j]));
    cv[j] = (1.f - zg) * ng + zg * bf2f((ushort_t)vh[j]);
    ps += cv[j];
  }
  float mean = wsum64(ps) * (1.0f / NG);
  float pq = 0.f;
#pragma unroll
  for (int j = 0; j < 8; j++) { float d = cv[j] - mean; pq += d * d; }
  float rstd = rsqrtf(wsum64(pq) * (1.0f / NG) + 1e-5f);
  float4 g0 = *(const float4*)&lng[f], g1 = *(const float4*)&lng[f + 4];
  float4 b0 = *(const float4*)&lnb[f], b1 = *(const float4*)&lnb[f + 4];
  float gg[8] = {g0.x, g0.y, g0.z, g0.w, g1.x, g1.y, g1.z, g1.w};
  float bbv[8] = {b0.x, b0.y, b0.z, b0.w, b1.x, b1.y, b1.z, b1.w};
  bf16x8 xo;
#pragma unroll
  for (int j = 0; j < 8; j++) xo[j] = (short)f2bf((cv[j] - mean) * rstd * gg[j] + bbv[j]);
  *(bf16x8*)&X0[(size_t)ltok * NG + f] = xo;
}

// ---------- final LN + score (wave per token) ----------
__global__ __launch_bounds__(256) void ln_score_kernel(
    const ushort_t* __restrict__ X, const float* __restrict__ lng,
    const float* __restrict__ lnb, const float* __restrict__ Wsc,
    const float* __restrict__ bsc, float* __restrict__ scores) {
  const int t = threadIdx.x;
  const int lane = t & 63, wv = t >> 6;
  const int ltok = blockIdx.x * 4 + wv;
  const int f = lane * 8;
  bf16x8 xx = *(const bf16x8*)&X[(size_t)ltok * ND + f];
  float x[8];
  float ps = 0.f;
#pragma unroll
  for (int j = 0; j < 8; j++) { x[j] = bf2f((ushort_t)xx[j]); ps += x[j]; }
  float mean = wsum64(ps) * (1.0f / ND);
  float pq = 0.f;
#pragma unroll
  for (int j = 0; j < 8; j++) { float d = x[j] - mean; pq += d * d; }
  float rstd = rsqrtf(wsum64(pq) * (1.0f / ND) + 1e-5f);
  float4 g0 = *(const float4*)&lng[f], g1 = *(const float4*)&lng[f + 4];
  float4 b0 = *(const float4*)&lnb[f], b1 = *(const float4*)&lnb[f + 4];
  float4 w0 = *(const float4*)&Wsc[f], w1 = *(const float4*)&Wsc[f + 4];
  float gg[8] = {g0.x, g0.y, g0.z, g0.w, g1.x, g1.y, g1.z, g1.w};
  float bbv[8] = {b0.x, b0.y, b0.z, b0.w, b1.x, b1.y, b1.z, b1.w};
  float ww[8] = {w0.x, w0.y, w0.z, w0.w, w1.x, w1.y, w1.z, w1.w};
  float d = 0.f;
#pragma unroll
  for (int j = 0; j < 8; j++) d += ((x[j] - mean) * rstd * gg[j] + bbv[j]) * ww[j];
  float dot = wsum64(d);
  if (lane == 0) scores[ltok] = dot + bsc[0];
}

// ---------- fused softmax + LDS-spectrum scatter (one block per batch) ----------
__global__ __launch_bounds__(256) void softmax_scatter_kernel(
    const float* __restrict__ scores, const int* __restrict__ pidx,
    const float* __restrict__ pint, float* __restrict__ spect,
    float* __restrict__ probs) {
  const int b = blockIdx.x;
  const int t = threadIdx.x;
  __shared__ float s_red[4];
  __shared__ float s_spec[NBINS];
  const float* sc = scores + (size_t)b * NS;
  float v[4];
  float mx = -1e30f;
#pragma unroll
  for (int i = 0; i < 4; i++) { v[i] = sc[t + i * 256]; mx = fmaxf(mx, v[i]); }
#pragma unroll
  for (int off = 32; off > 0; off >>= 1) mx = fmaxf(mx, __shfl_down(mx, off));
  if ((t & 63) == 0) s_red[t >> 6] = mx;
  __syncthreads();
  mx = fmaxf(fmaxf(s_red[0], s_red[1]), fmaxf(s_red[2], s_red[3]));
  float e[4], sum = 0.f;
#pragma unroll
  for (int i = 0; i < 4; i++) { e[i] = expf(v[i] - mx); sum += e[i]; }
#pragma unroll
  for (int off = 32; off > 0; off >>= 1) sum += __shfl_down(sum, off);
  __syncthreads();
  if ((t & 63) == 0) s_red[t >> 6] = sum;
  __syncthreads();
  sum = s_red[0] + s_red[1] + s_red[2] + s_red[3];
  float inv = 1.f / sum;
  s_spec[t] = 0.f; s_spec[t + 256] = 0.f;
  float p[4];
#pragma unroll
  for (int i = 0; i < 4; i++) {
    p[i] = e[i] * inv;
    probs[(size_t)b * NS + t + i * 256] = p[i];
  }
  __syncthreads();
#pragma unroll
  for (int i = 0; i < 4; i++) {
    const int s = t + i * 256;
    const int* idx = pidx + ((size_t)b * NS + s) * NM;
    const float* wt = pint + ((size_t)b * NS + s) * NM;
#pragma unroll
    for (int m = 0; m < NM; m++)
      atomicAdd(&s_spec[idx[m]], wt[m] * p[i]);
  }
  __syncthreads();
  spect[(size_t)b * NBINS + t] = s_spec[t];
  spect[(size_t)b * NBINS + t + 256] = s_spec[t + 256];
}

extern "C" void kernel_launch(void* const* d_in, const int* in_sizes, int n_in,
                              void* d_out, int out_size, void* d_ws, size_t ws_size,
                              hipStream_t stream) {
  const float* vert = (const float*)d_in[0];
  const float* mask = (const float*)d_in[1];
  const float* eloh = (const float*)d_in[2];
  const int* subs = (const int*)d_in[3];
  const int* pidx = (const int*)d_in[4];
  const float* pint = (const float*)d_in[5];
  const float* ln_sub_g = (const float*)d_in[6];
  const float* ln_sub_b = (const float*)d_in[7];
  const float* W_ih = (const float*)d_in[8];
  const float* W_hh = (const float*)d_in[9];
  const float* b_ih = (const float*)d_in[10];
  const float* b_hh = (const float*)d_in[11];
  const float* ln_post_g = (const float*)d_in[12];
  const float* ln_post_b = (const float*)d_in[13];
  const float* W1 = (const float*)d_in[14];
  const float* b1 = (const float*)d_in[15];
  const float* W2a = (const float*)d_in[16];
  const float* b2a = (const float*)d_in[17];
  const float* W2b = (const float*)d_in[18];
  const float* b2b = (const float*)d_in[19];
  const float* ln_pre_g = (const float*)d_in[20];
  const float* ln_pre_b = (const float*)d_in[21];
  const float* W_s = (const float*)d_in[22];
  const float* b_s = (const float*)d_in[23];

  float* out = (float*)d_out;            // [0,8192) spect, [8192,24576) probs
  float* probs = out + NB * NBINS;

  // ---- fixed region ----
  char* ws = (char*)d_ws;
  float* scores = (float*)ws;                       // 64 KB
  ushort_t* Whh_bf = (ushort_t*)(ws + 65536);       // 1536*512*2 = 1572864
  ushort_t* W1_bf  = (ushort_t*)(ws + 1638400);     // 512*512*2 = 524288
  ushort_t* W2a_bf = (ushort_t*)(ws + 2162688);
  ushort_t* W2b_bf = (ushort_t*)(ws + 2686976);
  ushort_t* VmT    = (ushort_t*)(ws + 3211264);     // 16*512*32*2 = 524288
  ushort_t* S_bf   = (ushort_t*)(ws + 3735552);     // 16384*32*2 = 1048576
  float*    tcd    = (float*)(ws + 4784128);        // 16384*8*4 = 524288
  ushort_t* PSb    = (ushort_t*)(ws + 5308416);     // 5*21*1536*2 = 322560
  const size_t fixed = 5630976;

  // ---- chunked region; per-token bytes: SWV 2048 | Hb 1024 | Gh 3072 | X0 1024 = 7168
  const size_t per_tok = 7168;
  int T = NTOK;
  while (T > 1024 && fixed + (size_t)T * per_tok > ws_size) T >>= 1;
  const int nchunks = NTOK / T;

  char* cb = ws + fixed;
  float*    SWV = (float*)cb;                             cb += (size_t)T * 2048;
  ushort_t* Hb  = (ushort_t*)cb;                          cb += (size_t)T * 1024;
  ushort_t* Gh  = (ushort_t*)cb;                          cb += (size_t)T * 3072;
  ushort_t* X0  = (ushort_t*)cb;
  ushort_t* X1  = Gh;                  // Gh dead after gate_ln
  ushort_t* X2  = Gh + (size_t)T * 512;
  ushort_t* X3  = X0;                  // X0 dead after W1 GEMM

  // fused setup: invcnt + PS prefix table + 4 weight cvts + VmT prep + S_bf cvt
  const int setup_items = NTOK + NE * 1536 + 1536 * NG + ND * NG + 2 * ND * ND
                        + NB * NG * NA + NTOK * NA;
  setup_kernel<<<(setup_items + 255) / 256, 256, 0, stream>>>(
      vert, mask, eloh, subs, W_ih, b_ih, W_hh, W1, W2a, W2b,
      tcd, PSb, Whh_bf, W1_bf, W2a_bf, W2b_bf, VmT, S_bf);

  for (int c = 0; c < nchunks; c++) {
    const int tok0 = c * T;

    dim3 gp(T / 128, NG / 128);
    pool_gemm<<<gp, 256, 0, stream>>>(S_bf, VmT, tcd, SWV, tok0);
    finish_kernel<<<T / 4, 256, 0, stream>>>(SWV, ln_sub_g, ln_sub_b, Hb);

    dim3 g1(T / 128, 1536 / 128);
    gemm_bf16<<<g1, 256, 0, stream>>>(Hb, Whh_bf, b_hh, Gh, NG, 1536, 3);

    gate_ln_kernel<<<T / 4, 256, 0, stream>>>(Gh, Hb, tcd + (size_t)tok0 * 8, PSb,
                                              ln_post_g, ln_post_b, X0);

    dim3 g2(T / 128, ND / 128);
    gemm_bf16<<<g2, 256, 0, stream>>>(X0, W1_bf, b1, X1, NG, ND, 1);
    gemm_bf16<<<g2, 256, 0, stream>>>(X1, W2a_bf, b2a, X2, ND, ND, 1);
    gemm_bf16<<<g2, 256, 0, stream>>>(X2, W2b_bf, b2b, X3, ND, ND, 1);

    ln_score_kernel<<<T / 4, 256, 0, stream>>>(X3, ln_pre_g, ln_pre_b, W_s, b_s,
                                               scores + tok0);
  }

  softmax_scatter_kernel<<<NB, 256, 0, stream>>>(scores, pidx, pint, out, probs);
}

// Round 13
// 241.940 us; speedup vs baseline: 1.0932x; 1.0373x over previous
//
#include <hip/hip_runtime.h>

#define NB 16
#define NA 32
#define NG 512
#define NS 1024
#define NM 8
#define NE 5
#define NOH 20
#define NFE 100
#define ND 512
#define NBINS 512
#define NTOK (NB * NS)

typedef unsigned short ushort_t;
typedef __attribute__((ext_vector_type(8))) short bf16x8;
typedef __attribute__((ext_vector_type(4))) float f32x4;

__device__ __forceinline__ ushort_t f2bf(float x) {
  union { float f; unsigned u; } v; v.f = x;
  unsigned r = v.u + 0x7FFF + ((v.u >> 16) & 1);   // RNE
  return (ushort_t)(r >> 16);
}
__device__ __forceinline__ float bf2f(ushort_t b) {
  union { unsigned u; float f; } v; v.u = ((unsigned)b) << 16;
  return v.f;
}

__device__ __forceinline__ void gload_lds16(const void* g, void* l) {
  __builtin_amdgcn_global_load_lds(
      (const __attribute__((address_space(1))) void*)g,
      (__attribute__((address_space(3))) void*)l, 16, 0, 0);
}

// wave-wide (64 lanes) butterfly sum; all lanes get result
__device__ __forceinline__ float wsum64(float v) {
#pragma unroll
  for (int off = 32; off > 0; off >>= 1) v += __shfl_xor(v, off);
  return v;
}

// fast native sigmoid/tanh (v_exp_f32 + v_rcp_f32; err ~1e-6 << bf16 rounding)
__device__ __forceinline__ float fsig(float x) {
  return __builtin_amdgcn_rcpf(1.f + __expf(-x));   // x<-88: exp->inf, rcp->0 (correct)
}
__device__ __forceinline__ float ftanh(float x) {
  float t = fminf(fmaxf(x, -15.f), 15.f);           // keep exp finite; tanh sat by |x|>9
  return 1.f - 2.f * __builtin_amdgcn_rcpf(__expf(2.f * t) + 1.f);
}

// ---------- fused setup: invcnt | PS prefix table (bf16, b_ih folded) | weight cvt | VmT | S_bf ----------
__global__ __launch_bounds__(256) void setup_kernel(
    const float* __restrict__ vert, const float* __restrict__ mask,
    const float* __restrict__ eloh, const int* __restrict__ subs,
    const float* __restrict__ Wih, const float* __restrict__ bih,
    const float* __restrict__ Whh,
    const float* __restrict__ W1, const float* __restrict__ W2a,
    const float* __restrict__ W2b,
    float* __restrict__ tcd, ushort_t* __restrict__ PSb,
    ushort_t* __restrict__ o_hh, ushort_t* __restrict__ o1,
    ushort_t* __restrict__ o2a, ushort_t* __restrict__ o2b,
    ushort_t* __restrict__ VmT, ushort_t* __restrict__ S_bf) {
  int i = blockIdx.x * 256 + threadIdx.x;
  if (i < NTOK) {   // per-token subset-size inverse + element counts (fp32 exact)
    int b = i >> 10;
    const int* srow = subs + (size_t)i * NA;
    float cnt[NE] = {0.f, 0.f, 0.f, 0.f, 0.f};
    float z = 0.f;
    for (int a = 0; a < NA; a++) {
      float sb = (float)srow[a];
      z += sb * mask[b * NA + a];
      const float* eo = eloh + (size_t)(b * NA + a) * NE;
#pragma unroll
      for (int e = 0; e < NE; e++) cnt[e] += eo[e] * sb;
    }
    float* o = tcd + (size_t)i * 8;
#pragma unroll
    for (int e = 0; e < NE; e++) o[e] = cnt[e];
    o[5] = 1.0f / (z + 1e-4f);
    return;
  }
  i -= NTOK;
  if (i < NE * 1536) {   // PSb[e][c][g] = bf16( (e==0?b_ih[g]:0) + sum_{o<c} W_ih[g][e*20+o] )
    int e = i / 1536, g = i % 1536;
    float s = (e == 0) ? bih[g] : 0.f;    // fold bias into element-0 row (all c)
    ushort_t* base = PSb + ((size_t)e * 21) * 1536 + g;
    base[0] = f2bf(s);
    for (int c = 1; c <= NOH; c++) {
      s += Wih[(size_t)g * NFE + e * NOH + (c - 1)];
      base[(size_t)c * 1536] = f2bf(s);
    }
    return;
  }
  i -= NE * 1536;
  if (i < 1536 * NG) { o_hh[i] = f2bf(Whh[i]); return; }
  i -= 1536 * NG;
  if (i < ND * NG) { o1[i] = f2bf(W1[i]); return; }
  i -= ND * NG;
  if (i < ND * ND) { o2a[i] = f2bf(W2a[i]); return; }
  i -= ND * ND;
  if (i < ND * ND) { o2b[i] = f2bf(W2b[i]); return; }
  i -= ND * ND;
  const int nV = NB * NG * NA;
  if (i < nV) {   // VmT[b][f][a] = bf16(vert*mask^2)
    int b = i / (NG * NA); int rem = i % (NG * NA);
    int f = rem >> 5, a = rem & 31;
    float mk = mask[b * NA + a];
    VmT[i] = f2bf(vert[(size_t)b * NA * NG + a * NG + f] * mk * mk);
    return;
  }
  i -= nV;
  if (i < NTOK * NA) S_bf[i] = f2bf((float)subs[i]);   // 0/1 exact
}

// ---------- fused pool GEMM + LN: Hb[ltok][f] = LN((subs @ VmT^T)*inv)  ----------
// BM=32 tokens, BN=512 (full f-range), K=32 single MFMA step. 4 waves; wave w owns
// f-cols [w*128, w*128+128). LN stats: in-register per-token partials -> 16-lane
// shfl_xor reduce -> cross-wave LDS reduce (fp32 exact). SWV never hits memory.
__global__ __launch_bounds__(256) void pool_ln_kernel(
    const ushort_t* __restrict__ S_bf, const ushort_t* __restrict__ VmT,
    const float* __restrict__ tcd, const float* __restrict__ lng,
    const float* __restrict__ lnb, ushort_t* __restrict__ Hb, int tok0) {
  __shared__ ushort_t Sb[32 * 32];     // 2 KB
  __shared__ ushort_t Vb[512 * 32];    // 32 KB (whole VmT[b] slice)
  __shared__ float red_s[4][32];
  __shared__ float red_q[4][32];
  const int t = threadIdx.x;
  const int w = t >> 6, lane = t & 63;
  const int bm = blockIdx.x * 32;      // chunk-local token base
  const int b = (tok0 + bm) >> 10;     // 32 | 1024 -> single batch per block
  const int scol = (((lane & 3) ^ ((lane >> 3) & 3)) * 8);   // pre-swizzled source chunk
  const int srow = lane >> 2;
  if (w < 2)   // Sb: 2 issues of 1KB (rows w*16..+15)
    gload_lds16(S_bf + (size_t)(tok0 + bm + w * 16 + srow) * 32 + scol, &Sb[(w * 16) * 32]);
  const ushort_t* Vg = VmT + (size_t)b * NG * NA;
#pragma unroll
  for (int i = 0; i < 8; i++)   // Vb: 8 issues x 4 waves: rows i*64+w*16..+15
    gload_lds16(Vg + (size_t)(i * 64 + w * 16 + srow) * 32 + scol, &Vb[(i * 64 + w * 16) * 32]);
  __syncthreads();

  const int lr = lane & 15, lq = lane >> 4;
  const int rchunk = (lq ^ ((lr >> 1) & 3)) * 8;   // swizzled read chunk
  bf16x8 a[2], bv[8];
#pragma unroll
  for (int m = 0; m < 2; m++)
    a[m] = *(const bf16x8*)&Sb[(m * 16 + lr) * 32 + rchunk];
#pragma unroll
  for (int n = 0; n < 8; n++)
    bv[n] = *(const bf16x8*)&Vb[(w * 128 + n * 16 + lr) * 32 + rchunk];
  f32x4 acc[2][8];
#pragma unroll
  for (int m = 0; m < 2; m++)
#pragma unroll
    for (int n = 0; n < 8; n++) {
      acc[m][n] = (f32x4)0.f;
      acc[m][n] = __builtin_amdgcn_mfma_f32_16x16x32_bf16(a[m], bv[n], acc[m][n], 0, 0, 0);
    }

  // scale by inv(subset size); per-token LN partials over this wave's 128 cols
  float ps[2][4], pq[2][4];
#pragma unroll
  for (int m = 0; m < 2; m++)
#pragma unroll
    for (int r = 0; r < 4; r++) {
      const int token = m * 16 + lq * 4 + r;
      const float inv = tcd[(size_t)(tok0 + bm + token) * 8 + 5];
      float s = 0.f, q = 0.f;
#pragma unroll
      for (int n = 0; n < 8; n++) {
        float v = acc[m][n][r] * inv;
        acc[m][n][r] = v;
        s += v; q += v * v;
      }
      ps[m][r] = s; pq[m][r] = q;
    }
  // reduce across the 16 lanes (lr) of each row-group
#pragma unroll
  for (int off = 1; off < 16; off <<= 1) {
#pragma unroll
    for (int m = 0; m < 2; m++)
#pragma unroll
      for (int r = 0; r < 4; r++) {
        ps[m][r] += __shfl_xor(ps[m][r], off);
        pq[m][r] += __shfl_xor(pq[m][r], off);
      }
  }
  if (lr == 0) {
#pragma unroll
    for (int m = 0; m < 2; m++)
#pragma unroll
      for (int r = 0; r < 4; r++) {
        red_s[w][m * 16 + lq * 4 + r] = ps[m][r];
        red_q[w][m * 16 + lq * 4 + r] = pq[m][r];
      }
  }
  __syncthreads();
  // finalize LN and write Hb bf16
#pragma unroll
  for (int m = 0; m < 2; m++)
#pragma unroll
    for (int r = 0; r < 4; r++) {
      const int token = m * 16 + lq * 4 + r;
      float tot = red_s[0][token] + red_s[1][token] + red_s[2][token] + red_s[3][token];
      float totq = red_q[0][token] + red_q[1][token] + red_q[2][token] + red_q[3][token];
      float mean = tot * (1.0f / NG);
      float var = totq * (1.0f / NG) - mean * mean;
      float rstd = rsqrtf(var + 1e-5f);
      ushort_t* hrow = Hb + (size_t)(bm + token) * NG;
#pragma unroll
      for (int n = 0; n < 8; n++) {
        const int f = w * 128 + n * 16 + lr;
        hrow[f] = f2bf((acc[m][n][r] - mean) * rstd * lng[f] + lnb[f]);
      }
    }
}

// ---------- bf16 MFMA GEMM, 2-phase double-buffer (compiler-scheduled) ----------
// BM=BN=128, BK=32, 4 waves (2x2), 4x4 16x16x32 frags per wave.
// mode: 1 = bf16 out relu, 3 = bf16 out no act
__global__ __launch_bounds__(256) void gemm_bf16(
    const ushort_t* __restrict__ A, const ushort_t* __restrict__ W,
    const float* __restrict__ bias, ushort_t* __restrict__ C,
    int K, int Dout, int mode) {
  __shared__ ushort_t As[2][4096];
  __shared__ ushort_t Bs[2][4096];
  const int t = threadIdx.x;
  const int w = t >> 6;
  const int lane = t & 63;
  const int wr = w >> 1, wc = w & 1;
  const int bm = blockIdx.x * 128, bn = blockIdx.y * 128;

  const int srow = lane >> 2;
  const int scol = (((lane & 3) ^ ((lane >> 3) & 3)) * 8);   // pre-swizzled source chunk
  const ushort_t* Ag0 = A + (size_t)(bm + w * 16 + srow) * K + scol;
  const ushort_t* Ag1 = A + (size_t)(bm + 64 + w * 16 + srow) * K + scol;
  const ushort_t* Wg0 = W + (size_t)(bn + w * 16 + srow) * K + scol;
  const ushort_t* Wg1 = W + (size_t)(bn + 64 + w * 16 + srow) * K + scol;
  const int l0 = w * 512;          // ushort offset, issue 0 (rows w*16..+16)
  const int l1 = 2048 + w * 512;   // issue 1 (rows 64+w*16..+16)

  const int lr = lane & 15;
  const int lq = lane >> 4;
  const int rchunk = (lq ^ ((lr >> 1) & 3)) * 8;   // swizzled read chunk

  f32x4 acc[4][4];
#pragma unroll
  for (int m = 0; m < 4; m++)
#pragma unroll
    for (int n = 0; n < 4; n++) acc[m][n] = (f32x4)0.f;

  // prologue: stage tile 0 into buf 0
  gload_lds16(Ag0, &As[0][l0]);
  gload_lds16(Ag1, &As[0][l1]);
  gload_lds16(Wg0, &Bs[0][l0]);
  gload_lds16(Wg1, &Bs[0][l1]);
  __syncthreads();

  const int nk = K >> 5;
  int cur = 0;
  for (int kt = 0; kt < nk; kt++) {
    if (kt + 1 < nk) {            // prefetch next tile into other buffer
      const int k1 = (kt + 1) << 5;
      gload_lds16(Ag0 + k1, &As[cur ^ 1][l0]);
      gload_lds16(Ag1 + k1, &As[cur ^ 1][l1]);
      gload_lds16(Wg0 + k1, &Bs[cur ^ 1][l0]);
      gload_lds16(Wg1 + k1, &Bs[cur ^ 1][l1]);
    }
    bf16x8 a[4], b[4];
#pragma unroll
    for (int m = 0; m < 4; m++)
      a[m] = *(const bf16x8*)&As[cur][(wr * 64 + m * 16 + lr) * 32 + rchunk];
#pragma unroll
    for (int n = 0; n < 4; n++)
      b[n] = *(const bf16x8*)&Bs[cur][(wc * 64 + n * 16 + lr) * 32 + rchunk];
#pragma unroll
    for (int m = 0; m < 4; m++)
#pragma unroll
      for (int n = 0; n < 4; n++)
        acc[m][n] = __builtin_amdgcn_mfma_f32_16x16x32_bf16(a[m], b[n], acc[m][n], 0, 0, 0);
    __syncthreads();   // drains lgkm (buf reads) and vm (prefetch) before swap
    cur ^= 1;
  }

  // ---- epilogue: per-wave LDS re-stage -> coalesced stores ----
  ushort_t* sc = (w < 2) ? &As[w][0] : &Bs[w - 2][0];   // 4096 ushorts = 64x64 tile
#pragma unroll
  for (int n = 0; n < 4; n++) {
    const float bv = bias[bn + wc * 64 + n * 16 + lr];
#pragma unroll
    for (int m = 0; m < 4; m++) {
      f32x4 v = acc[m][n];
#pragma unroll
      for (int r = 0; r < 4; r++) {
        const int row = m * 16 + lq * 4 + r;
        float u = v[r] + bv;
        if (mode == 1) u = fmaxf(u, 0.f);
        sc[row * 64 + ((n * 16 + lr) ^ ((row & 7) << 3))] = f2bf(u);
      }
    }
  }
  __builtin_amdgcn_s_waitcnt(0);   // lgkmcnt(0): ds_writes visible to own-wave reads
#pragma unroll
  for (int p = 0; p < 8; p++) {
    const int row = p * 8 + (lane >> 3);
    bf16x8 pk = *(const bf16x8*)&sc[row * 64 + (((lane & 7) * 8) ^ ((row & 7) << 3))];
    *(bf16x8*)&C[(size_t)(bm + wr * 64 + row) * Dout + bn + wc * 64 + (lane & 7) * 8] = pk;
  }
}

// ---------- GRU gates + post-LN, gi via bf16 PS gather (bias folded) ----------
__global__ __launch_bounds__(256) void gate_ln_kernel(
    const ushort_t* __restrict__ Gh, const ushort_t* __restrict__ Hb,
    const float* __restrict__ tcd, const ushort_t* __restrict__ PSb,
    const float* __restrict__ lng, const float* __restrict__ lnb,
    ushort_t* __restrict__ X0) {
  const int t = threadIdx.x;
  const int lane = t & 63, wv = t >> 6;
  const int ltok = blockIdx.x * 4 + wv;
  const int f = lane * 8;
  int c[NE];
#pragma unroll
  for (int e = 0; e < NE; e++) {
    int ci = (int)tcd[(size_t)ltok * 8 + e];   // exact integer-valued fp32
    c[e] = ci > NOH ? NOH : ci;
  }
  float gir[8] = {0.f, 0.f, 0.f, 0.f, 0.f, 0.f, 0.f, 0.f};
  float giz[8] = {0.f, 0.f, 0.f, 0.f, 0.f, 0.f, 0.f, 0.f};
  float gin[8] = {0.f, 0.f, 0.f, 0.f, 0.f, 0.f, 0.f, 0.f};
#pragma unroll
  for (int e = 0; e < NE; e++) {
    const ushort_t* pe = PSb + ((size_t)(e * 21 + c[e])) * 1536;
    bf16x8 pr = *(const bf16x8*)&pe[f];
    bf16x8 pz = *(const bf16x8*)&pe[NG + f];
    bf16x8 pn = *(const bf16x8*)&pe[2 * NG + f];
#pragma unroll
    for (int j = 0; j < 8; j++) {
      gir[j] += bf2f((ushort_t)pr[j]);
      giz[j] += bf2f((ushort_t)pz[j]);
      gin[j] += bf2f((ushort_t)pn[j]);
    }
  }

  const ushort_t* gh = Gh + (size_t)ltok * 1536;
  bf16x8 vr = *(const bf16x8*)&gh[f];
  bf16x8 vz = *(const bf16x8*)&gh[NG + f];
  bf16x8 vn = *(const bf16x8*)&gh[2 * NG + f];
  bf16x8 vh = *(const bf16x8*)&Hb[(size_t)ltok * NG + f];
  float cv[8];
  float ps = 0.f;
#pragma unroll
  for (int j = 0; j < 8; j++) {
    float rg = fsig(gir[j] + bf2f((ushort_t)vr[j]));
    float zg = fsig(giz[j] + bf2f((ushort_t)vz[j]));
    float ng = ftanh(gin[j] + rg * bf2f((ushort_t)vn[j]));
    cv[j] = (1.f - zg) * ng + zg * bf2f((ushort_t)vh[j]);
    ps += cv[j];
  }
  float mean = wsum64(ps) * (1.0f / NG);
  float pq = 0.f;
#pragma unroll
  for (int j = 0; j < 8; j++) { float d = cv[j] - mean; pq += d * d; }
  float rstd = rsqrtf(wsum64(pq) * (1.0f / NG) + 1e-5f);
  float4 g0 = *(const float4*)&lng[f], g1 = *(const float4*)&lng[f + 4];
  float4 b0 = *(const float4*)&lnb[f], b1 = *(const float4*)&lnb[f + 4];
  float gg[8] = {g0.x, g0.y, g0.z, g0.w, g1.x, g1.y, g1.z, g1.w};
  float bbv[8] = {b0.x, b0.y, b0.z, b0.w, b1.x, b1.y, b1.z, b1.w};
  bf16x8 xo;
#pragma unroll
  for (int j = 0; j < 8; j++) xo[j] = (short)f2bf((cv[j] - mean) * rstd * gg[j] + bbv[j]);
  *(bf16x8*)&X0[(size_t)ltok * NG + f] = xo;
}

// ---------- final LN + score (wave per token) ----------
__global__ __launch_bounds__(256) void ln_score_kernel(
    const ushort_t* __restrict__ X, const float* __restrict__ lng,
    const float* __restrict__ lnb, const float* __restrict__ Wsc,
    const float* __restrict__ bsc, float* __restrict__ scores) {
  const int t = threadIdx.x;
  const int lane = t & 63, wv = t >> 6;
  const int ltok = blockIdx.x * 4 + wv;
  const int f = lane * 8;
  bf16x8 xx = *(const bf16x8*)&X[(size_t)ltok * ND + f];
  float x[8];
  float ps = 0.f;
#pragma unroll
  for (int j = 0; j < 8; j++) { x[j] = bf2f((ushort_t)xx[j]); ps += x[j]; }
  float mean = wsum64(ps) * (1.0f / ND);
  float pq = 0.f;
#pragma unroll
  for (int j = 0; j < 8; j++) { float d = x[j] - mean; pq += d * d; }
  float rstd = rsqrtf(wsum64(pq) * (1.0f / ND) + 1e-5f);
  float4 g0 = *(const float4*)&lng[f], g1 = *(const float4*)&lng[f + 4];
  float4 b0 = *(const float4*)&lnb[f], b1 = *(const float4*)&lnb[f + 4];
  float4 w0 = *(const float4*)&Wsc[f], w1 = *(const float4*)&Wsc[f + 4];
  float gg[8] = {g0.x, g0.y, g0.z, g0.w, g1.x, g1.y, g1.z, g1.w};
  float bbv[8] = {b0.x, b0.y, b0.z, b0.w, b1.x, b1.y, b1.z, b1.w};
  float ww[8] = {w0.x, w0.y, w0.z, w0.w, w1.x, w1.y, w1.z, w1.w};
  float d = 0.f;
#pragma unroll
  for (int j = 0; j < 8; j++) d += ((x[j] - mean) * rstd * gg[j] + bbv[j]) * ww[j];
  float dot = wsum64(d);
  if (lane == 0) scores[ltok] = dot + bsc[0];
}

// ---------- fused softmax + LDS-spectrum scatter (one block per batch) ----------
__global__ __launch_bounds__(256) void softmax_scatter_kernel(
    const float* __restrict__ scores, const int* __restrict__ pidx,
    const float* __restrict__ pint, float* __restrict__ spect,
    float* __restrict__ probs) {
  const int b = blockIdx.x;
  const int t = threadIdx.x;
  __shared__ float s_red[4];
  __shared__ float s_spec[NBINS];
  const float* sc = scores + (size_t)b * NS;
  float v[4];
  float mx = -1e30f;
#pragma unroll
  for (int i = 0; i < 4; i++) { v[i] = sc[t + i * 256]; mx = fmaxf(mx, v[i]); }
#pragma unroll
  for (int off = 32; off > 0; off >>= 1) mx = fmaxf(mx, __shfl_down(mx, off));
  if ((t & 63) == 0) s_red[t >> 6] = mx;
  __syncthreads();
  mx = fmaxf(fmaxf(s_red[0], s_red[1]), fmaxf(s_red[2], s_red[3]));
  float e[4], sum = 0.f;
#pragma unroll
  for (int i = 0; i < 4; i++) { e[i] = expf(v[i] - mx); sum += e[i]; }
#pragma unroll
  for (int off = 32; off > 0; off >>= 1) sum += __shfl_down(sum, off);
  __syncthreads();
  if ((t & 63) == 0) s_red[t >> 6] = sum;
  __syncthreads();
  sum = s_red[0] + s_red[1] + s_red[2] + s_red[3];
  float inv = 1.f / sum;
  s_spec[t] = 0.f; s_spec[t + 256] = 0.f;
  float p[4];
#pragma unroll
  for (int i = 0; i < 4; i++) {
    p[i] = e[i] * inv;
    probs[(size_t)b * NS + t + i * 256] = p[i];
  }
  __syncthreads();
#pragma unroll
  for (int i = 0; i < 4; i++) {
    const int s = t + i * 256;
    const int* idx = pidx + ((size_t)b * NS + s) * NM;
    const float* wt = pint + ((size_t)b * NS + s) * NM;
#pragma unroll
    for (int m = 0; m < NM; m++)
      atomicAdd(&s_spec[idx[m]], wt[m] * p[i]);
  }
  __syncthreads();
  spect[(size_t)b * NBINS + t] = s_spec[t];
  spect[(size_t)b * NBINS + t + 256] = s_spec[t + 256];
}

extern "C" void kernel_launch(void* const* d_in, const int* in_sizes, int n_in,
                              void* d_out, int out_size, void* d_ws, size_t ws_size,
                              hipStream_t stream) {
  const float* vert = (const float*)d_in[0];
  const float* mask = (const float*)d_in[1];
  const float* eloh = (const float*)d_in[2];
  const int* subs = (const int*)d_in[3];
  const int* pidx = (const int*)d_in[4];
  const float* pint = (const float*)d_in[5];
  const float* ln_sub_g = (const float*)d_in[6];
  const float* ln_sub_b = (const float*)d_in[7];
  const float* W_ih = (const float*)d_in[8];
  const float* W_hh = (const float*)d_in[9];
  const float* b_ih = (const float*)d_in[10];
  const float* b_hh = (const float*)d_in[11];
  const float* ln_post_g = (const float*)d_in[12];
  const float* ln_post_b = (const float*)d_in[13];
  const float* W1 = (const float*)d_in[14];
  const float* b1 = (const float*)d_in[15];
  const float* W2a = (const float*)d_in[16];
  const float* b2a = (const float*)d_in[17];
  const float* W2b = (const float*)d_in[18];
  const float* b2b = (const float*)d_in[19];
  const float* ln_pre_g = (const float*)d_in[20];
  const float* ln_pre_b = (const float*)d_in[21];
  const float* W_s = (const float*)d_in[22];
  const float* b_s = (const float*)d_in[23];

  float* out = (float*)d_out;            // [0,8192) spect, [8192,24576) probs
  float* probs = out + NB * NBINS;

  // ---- fixed region ----
  char* ws = (char*)d_ws;
  float* scores = (float*)ws;                       // 64 KB
  ushort_t* Whh_bf = (ushort_t*)(ws + 65536);       // 1536*512*2 = 1572864
  ushort_t* W1_bf  = (ushort_t*)(ws + 1638400);     // 512*512*2 = 524288
  ushort_t* W2a_bf = (ushort_t*)(ws + 2162688);
  ushort_t* W2b_bf = (ushort_t*)(ws + 2686976);
  ushort_t* VmT    = (ushort_t*)(ws + 3211264);     // 16*512*32*2 = 524288
  ushort_t* S_bf   = (ushort_t*)(ws + 3735552);     // 16384*32*2 = 1048576
  float*    tcd    = (float*)(ws + 4784128);        // 16384*8*4 = 524288
  ushort_t* PSb    = (ushort_t*)(ws + 5308416);     // 5*21*1536*2 = 322560
  const size_t fixed = 5630976;

  // ---- chunked region; per-token bytes: Hb 1024 | Gh 3072 | X0 1024 = 5120
  const size_t per_tok = 5120;
  int T = NTOK;
  while (T > 1024 && fixed + (size_t)T * per_tok > ws_size) T >>= 1;
  const int nchunks = NTOK / T;

  char* cb = ws + fixed;
  ushort_t* Hb  = (ushort_t*)cb;                          cb += (size_t)T * 1024;
  ushort_t* Gh  = (ushort_t*)cb;                          cb += (size_t)T * 3072;
  ushort_t* X0  = (ushort_t*)cb;
  ushort_t* X1  = Gh;                  // Gh dead after gate_ln
  ushort_t* X2  = Gh + (size_t)T * 512;
  ushort_t* X3  = X0;                  // X0 dead after W1 GEMM

  // fused setup: invcnt + PS prefix table + 4 weight cvts + VmT prep + S_bf cvt
  const int setup_items = NTOK + NE * 1536 + 1536 * NG + ND * NG + 2 * ND * ND
                        + NB * NG * NA + NTOK * NA;
  setup_kernel<<<(setup_items + 255) / 256, 256, 0, stream>>>(
      vert, mask, eloh, subs, W_ih, b_ih, W_hh, W1, W2a, W2b,
      tcd, PSb, Whh_bf, W1_bf, W2a_bf, W2b_bf, VmT, S_bf);

  for (int c = 0; c < nchunks; c++) {
    const int tok0 = c * T;

    pool_ln_kernel<<<T / 32, 256, 0, stream>>>(S_bf, VmT, tcd, ln_sub_g, ln_sub_b,
                                               Hb, tok0);

    dim3 g1(T / 128, 1536 / 128);
    gemm_bf16<<<g1, 256, 0, stream>>>(Hb, Whh_bf, b_hh, Gh, NG, 1536, 3);

    gate_ln_kernel<<<T / 4, 256, 0, stream>>>(Gh, Hb, tcd + (size_t)tok0 * 8, PSb,
                                              ln_post_g, ln_post_b, X0);

    dim3 g2(T / 128, ND / 128);
    gemm_bf16<<<g2, 256, 0, stream>>>(X0, W1_bf, b1, X1, NG, ND, 1);
    gemm_bf16<<<g2, 256, 0, stream>>>(X1, W2a_bf, b2a, X2, ND, ND, 1);
    gemm_bf16<<<g2, 256, 0, stream>>>(X2, W2b_bf, b2b, X3, ND, ND, 1);

    ln_score_kernel<<<T / 4, 256, 0, stream>>>(X3, ln_pre_g, ln_pre_b, W_s, b_s,
                                               scores + tok0);
  }

  softmax_scatter_kernel<<<NB, 256, 0, stream>>>(scores, pidx, pint, out, probs);
}